// Round 5
// baseline (886.038 us; speedup 1.0000x reference)
//
#include <hip/hip_runtime.h>

typedef short bf16x8 __attribute__((ext_vector_type(8)));
typedef float f32x4  __attribute__((ext_vector_type(4)));

#define T_TOK 16384
#define HD 768
#define ID 3072
#define NE 8
#define NTM 264          // max 128-row tiles: 32768/128 + 8 partials

__device__ __forceinline__ unsigned short f2bf(float f) {
    unsigned int u = __float_as_uint(f);
    unsigned int r = (u + 0x7FFFu + ((u >> 16) & 1u)) >> 16;   // RNE
    return (unsigned short)r;
}

__device__ __forceinline__ void gload16(const void* g, void* l) {
    __builtin_amdgcn_global_load_lds(
        (const __attribute__((address_space(1))) void*)g,
        (__attribute__((address_space(3))) void*)l, 16, 0, 0);
}

__device__ __forceinline__ float gelu_f(float x) {
    // exact-GELU via A&S 7.1.26 erf approx (|err| <= 1.5e-7, invisible at bf16)
    float z = fabsf(x) * 0.70710678118f;
    float t = 1.0f / fmaf(0.3275911f, z, 1.0f);
    float p = t * fmaf(t, fmaf(t, fmaf(t, fmaf(t, 1.061405429f, -1.453152027f),
                                       1.421413741f), -0.284496736f), 0.254829592f);
    float e = 1.0f - p * __expf(-z * z);
    float erfv = (x >= 0.f) ? e : -e;
    return 0.5f * x * (1.0f + erfv);
}

__device__ __forceinline__ int xcd_swz(int bid, int nwg) {
    // bijective XCD-chunked remap (m204)
    int q = nwg >> 3, rr = nwg & 7;
    int xcd = bid & 7, seq = bid >> 3;
    return (xcd < rr ? xcd * (q + 1) : rr * (q + 1) + (xcd - rr) * q) + seq;
}

// ---------------- x f32 -> bf16 ----------------
__global__ __launch_bounds__(256) void k_cvt_x(const float* __restrict__ x,
                                               unsigned short* __restrict__ xb) {
    int i = blockIdx.x * 256 + threadIdx.x;
    float4 v = ((const float4*)x)[i];
    ushort4 o;
    o.x = f2bf(v.x); o.y = f2bf(v.y); o.z = f2bf(v.z); o.w = f2bf(v.w);
    ((ushort4*)xb)[i] = o;
}

// ---------------- transpose + cvt: in [E][R][C] f32 -> out [E][C][R] bf16 ----
__global__ __launch_bounds__(256) void k_tp(const float* __restrict__ in,
                                            unsigned short* __restrict__ out,
                                            int R, int C) {
    __shared__ float t[64][65];
    const float* ine = in + (size_t)blockIdx.z * R * C;
    unsigned short* oute = out + (size_t)blockIdx.z * R * C;
    int c0 = blockIdx.x * 64, r0 = blockIdx.y * 64;
    int lc = threadIdx.x & 63, lr4 = threadIdx.x >> 6;
#pragma unroll
    for (int i = 0; i < 16; i++) {
        int r = i * 4 + lr4;
        t[r][lc] = ine[(size_t)(r0 + r) * C + c0 + lc];
    }
    __syncthreads();
#pragma unroll
    for (int i = 0; i < 16; i++) {
        int r = i * 4 + lr4;
        oute[(size_t)(c0 + r) * R + r0 + lc] = f2bf(t[lc][r]);
    }
}

// ---------------- router: wave per token, f32 ----------------
__global__ __launch_bounds__(256) void k_router(const float* __restrict__ x,
                                                const float* __restrict__ rw,
                                                int* __restrict__ topE,
                                                float* __restrict__ topW) {
    __shared__ float lrw[NE * HD];
    for (int i = threadIdx.x; i < NE * HD; i += 256) lrw[i] = rw[i];
    __syncthreads();
    int lane = threadIdx.x & 63;
    int t = blockIdx.x * 4 + (threadIdx.x >> 6);
    const float* xr = x + (size_t)t * HD;
    float acc[NE] = {0, 0, 0, 0, 0, 0, 0, 0};
    for (int h = lane; h < HD; h += 64) {
        float xv = xr[h];
#pragma unroll
        for (int e = 0; e < NE; e++) acc[e] = fmaf(xv, lrw[e * HD + h], acc[e]);
    }
#pragma unroll
    for (int e = 0; e < NE; e++) {
        float v = acc[e];
#pragma unroll
        for (int o = 32; o > 0; o >>= 1) v += __shfl_xor(v, o, 64);
        acc[e] = v;
    }
    if (lane == 0) {
        int e1 = 0; float l1 = acc[0];
#pragma unroll
        for (int e = 1; e < NE; e++) if (acc[e] > l1) { l1 = acc[e]; e1 = e; }
        int e2 = -1; float l2 = -1e30f;
#pragma unroll
        for (int e = 0; e < NE; e++) if (e != e1 && acc[e] > l2) { l2 = acc[e]; e2 = e; }
        float ex = expf(l2 - l1);
        float w1 = 1.0f / (1.0f + ex);
        topE[2 * t] = e1; topE[2 * t + 1] = e2;
        topW[2 * t] = w1; topW[2 * t + 1] = ex * w1;
    }
}

// ---------------- scatter into per-expert lists ----------------
__global__ __launch_bounds__(256) void k_scatter(const int* __restrict__ topE,
                                                 const float* __restrict__ topW,
                                                 int* __restrict__ counts,
                                                 int* __restrict__ tokL,
                                                 float* __restrict__ gateL) {
    __shared__ int lc[NE], lbase[NE];
    if (threadIdx.x < NE) lc[threadIdx.x] = 0;
    __syncthreads();
    int t = blockIdx.x * 256 + threadIdx.x;
    int e1 = topE[2 * t], e2 = topE[2 * t + 1];
    int p1 = atomicAdd(&lc[e1], 1);
    int p2 = atomicAdd(&lc[e2], 1);
    __syncthreads();
    if (threadIdx.x < NE) lbase[threadIdx.x] = atomicAdd(&counts[threadIdx.x], lc[threadIdx.x]);
    __syncthreads();
    int q1 = lbase[e1] + p1, q2 = lbase[e2] + p2;
    tokL[e1 * T_TOK + q1] = t;  gateL[e1 * T_TOK + q1] = topW[2 * t];
    tokL[e2 * T_TOK + q2] = t;  gateL[e2 * T_TOK + q2] = topW[2 * t + 1];
}

// ---------------- tile descriptor build: 128-row tiles ----------------
__global__ void k_desc(const int* __restrict__ counts, int* __restrict__ tileE,
                       int* __restrict__ tileM0) {
    if (threadIdx.x == 0 && blockIdx.x == 0) {
        int tl = 0;
        for (int e = 0; e < NE; e++) {
            int c = counts[e];
            int nt = (c + 127) >> 7;
            for (int t = 0; t < nt; t++) { tileE[tl] = e; tileM0[tl] = t << 7; tl++; }
        }
        for (; tl < NTM; tl++) { tileE[tl] = -1; tileM0[tl] = 0; }
    }
}

// ============ grouped GEMM1: h_seg = gelu( Xg[128xH] @ up_seg[128xH]^T ) ============
// 128x128 tile, BK=64, 4 waves, 2x32KB LDS double-buffer, prefetch-1:
// STAGE(k+1) -> compute(k) -> vmcnt(0)+barrier. Loads get a full compute phase to land.
// LDS chunk c (1KB): operand rows [(c>>1)*16..+15], k-half c&1; within: [kgrp4][row16]x16B
// -> every gload dst and every ds_read_b128 is linear-1KB per wave (conflict-free).
__global__ __launch_bounds__(256, 2) void k_gemm1(
    const unsigned short* __restrict__ xb,
    const unsigned short* __restrict__ upt,     // [E][I][H] bf16
    const int* __restrict__ tokL,
    const int* __restrict__ counts,
    const int* __restrict__ tileE,
    const int* __restrict__ tileM0,
    unsigned short* __restrict__ h,             // [NTM*128][ldh]
    int segI, int ntn, int ldh) {
    __shared__ __align__(16) char lds[2][32768];   // per buf: A @0, B @16384
    constexpr int NK = HD / 64;                 // 12
    int L = xcd_swz(blockIdx.x, gridDim.x);
    int mt = L / ntn, ntl = L - mt * ntn;
    int e = tileE[mt];
    if (e < 0) return;
    int m0 = tileM0[mt];
    int nrow = min(128, counts[e] - m0);
    const int* tok = tokL + e * T_TOK + m0;

    const int tid = threadIdx.x, lane = tid & 63, wid = tid >> 6;
    const int wm = wid >> 1, wn = wid & 1;
    const int g = lane >> 4, r = lane & 15;

    const char* bsl = (const char*)(upt + (size_t)e * ID * HD);
    const char* asrc[4];
    const char* bsrc[4];
#pragma unroll
    for (int j = 0; j < 4; j++) {
        int c = wid * 4 + j;
        int row = (c >> 1) * 16 + r;
        int kb0 = (c & 1) * 64 + g * 16;
        asrc[j] = (const char*)xb + (size_t)tok[row < nrow ? row : 0] * (HD * 2) + kb0;
        bsrc[j] = bsl + (size_t)(segI + ntl * 128 + row) * (HD * 2) + kb0;
    }
    const int dst = wid * 4096;                 // 4 chunks per wave; HW adds lane*16

    f32x4 acc[4][4];
#pragma unroll
    for (int m = 0; m < 4; m++)
#pragma unroll
        for (int n = 0; n < 4; n++) acc[m][n] = (f32x4){0.f, 0.f, 0.f, 0.f};

    const int foff = g * 256 + r * 16;

    // prologue: stage step 0 into buf 0
#pragma unroll
    for (int j = 0; j < 4; j++) gload16(asrc[j], &lds[0][0] + dst + j * 1024);
#pragma unroll
    for (int j = 0; j < 4; j++) gload16(bsrc[j], &lds[0][0] + 16384 + dst + j * 1024);
#pragma unroll
    for (int j = 0; j < 4; j++) { asrc[j] += 128; bsrc[j] += 128; }
    asm volatile("s_waitcnt vmcnt(0)" ::: "memory");
    __builtin_amdgcn_s_barrier();
    asm volatile("" ::: "memory");

    for (int k = 0; k < NK; k++) {
        char* cur = &lds[k & 1][0];
        char* nxt = &lds[(k + 1) & 1][0];
        if (k + 1 < NK) {   // prefetch next step (previous end-barrier made nxt safe)
#pragma unroll
            for (int j = 0; j < 4; j++) gload16(asrc[j], nxt + dst + j * 1024);
#pragma unroll
            for (int j = 0; j < 4; j++) gload16(bsrc[j], nxt + 16384 + dst + j * 1024);
#pragma unroll
            for (int j = 0; j < 4; j++) { asrc[j] += 128; bsrc[j] += 128; }
        }
#pragma unroll
        for (int kh = 0; kh < 2; kh++) {
            bf16x8 a[4], b[4];
#pragma unroll
            for (int n = 0; n < 4; n++)
                b[n] = *(const bf16x8*)(cur + 16384 + ((wn * 4 + n) * 2 + kh) * 1024 + foff);
#pragma unroll
            for (int m = 0; m < 4; m++)
                a[m] = *(const bf16x8*)(cur + ((wm * 4 + m) * 2 + kh) * 1024 + foff);
            __builtin_amdgcn_s_setprio(1);
#pragma unroll
            for (int m = 0; m < 4; m++)
#pragma unroll
                for (int n = 0; n < 4; n++)
                    acc[m][n] = __builtin_amdgcn_mfma_f32_16x16x32_bf16(a[m], b[n], acc[m][n], 0, 0, 0);
            __builtin_amdgcn_s_setprio(0);
        }
        asm volatile("s_waitcnt vmcnt(0)" ::: "memory");   // prefetch landed
        __builtin_amdgcn_s_barrier();
        asm volatile("" ::: "memory");
    }

#pragma unroll
    for (int m = 0; m < 4; m++)
#pragma unroll
        for (int j = 0; j < 4; j++) {
            int rl = wm * 64 + m * 16 + g * 4 + j;
            if (rl < nrow) {
                unsigned short* hr = h + (size_t)(mt * 128 + rl) * ldh + ntl * 128 + wn * 64 + r;
#pragma unroll
                for (int n = 0; n < 4; n++) hr[n * 16] = f2bf(gelu_f(acc[m][n][j]));
            }
        }
}

// ============ grouped GEMM2: out[tok] += gate * ( h_seg @ down_seg[128xldh]^T ) ====
__global__ __launch_bounds__(256, 2) void k_gemm2(
    const unsigned short* __restrict__ h,       // [NTM*128][ldh]
    const unsigned short* __restrict__ dnt,     // [E][H][I] bf16
    const int* __restrict__ tokL,
    const float* __restrict__ gateL,
    const int* __restrict__ counts,
    const int* __restrict__ tileE,
    const int* __restrict__ tileM0,
    float* __restrict__ out,
    int segI, int ldh, int nk) {
    __shared__ __align__(16) char lds[2][32768];
    int L = xcd_swz(blockIdx.x, gridDim.x);
    int mt = L / 6, ntl = L - mt * 6;
    int e = tileE[mt];
    if (e < 0) return;
    int m0 = tileM0[mt];
    int nrow = min(128, counts[e] - m0);
    const int* tok = tokL + e * T_TOK + m0;
    const float* gat = gateL + e * T_TOK + m0;
    int n0 = ntl * 128;

    const int tid = threadIdx.x, lane = tid & 63, wid = tid >> 6;
    const int wm = wid >> 1, wn = wid & 1;
    const int g = lane >> 4, r = lane & 15;

    const char* bsl = (const char*)(dnt + (size_t)e * ID * HD) + (size_t)segI * 2;
    const char* asrc[4];
    const char* bsrc[4];
#pragma unroll
    for (int j = 0; j < 4; j++) {
        int c = wid * 4 + j;
        int row = (c >> 1) * 16 + r;
        int kb0 = (c & 1) * 64 + g * 16;
        asrc[j] = (const char*)h + ((size_t)(mt * 128 + row) * ldh) * 2 + kb0;  // pad rows: row-isolated garbage
        bsrc[j] = bsl + (size_t)(n0 + row) * (ID * 2) + kb0;
    }
    const int dst = wid * 4096;

    f32x4 acc[4][4];
#pragma unroll
    for (int m = 0; m < 4; m++)
#pragma unroll
        for (int n = 0; n < 4; n++) acc[m][n] = (f32x4){0.f, 0.f, 0.f, 0.f};

    const int foff = g * 256 + r * 16;

    // prologue: stage step 0 into buf 0
#pragma unroll
    for (int j = 0; j < 4; j++) gload16(asrc[j], &lds[0][0] + dst + j * 1024);
#pragma unroll
    for (int j = 0; j < 4; j++) gload16(bsrc[j], &lds[0][0] + 16384 + dst + j * 1024);
#pragma unroll
    for (int j = 0; j < 4; j++) { asrc[j] += 128; bsrc[j] += 128; }
    asm volatile("s_waitcnt vmcnt(0)" ::: "memory");
    __builtin_amdgcn_s_barrier();
    asm volatile("" ::: "memory");

    for (int k = 0; k < nk; k++) {
        char* cur = &lds[k & 1][0];
        char* nxt = &lds[(k + 1) & 1][0];
        if (k + 1 < nk) {
#pragma unroll
            for (int j = 0; j < 4; j++) gload16(asrc[j], nxt + dst + j * 1024);
#pragma unroll
            for (int j = 0; j < 4; j++) gload16(bsrc[j], nxt + 16384 + dst + j * 1024);
#pragma unroll
            for (int j = 0; j < 4; j++) { asrc[j] += 128; bsrc[j] += 128; }
        }
#pragma unroll
        for (int kh = 0; kh < 2; kh++) {
            bf16x8 a[4], b[4];
#pragma unroll
            for (int n = 0; n < 4; n++)
                b[n] = *(const bf16x8*)(cur + 16384 + ((wn * 4 + n) * 2 + kh) * 1024 + foff);
#pragma unroll
            for (int m = 0; m < 4; m++)
                a[m] = *(const bf16x8*)(cur + ((wm * 4 + m) * 2 + kh) * 1024 + foff);
            __builtin_amdgcn_s_setprio(1);
#pragma unroll
            for (int m = 0; m < 4; m++)
#pragma unroll
                for (int n = 0; n < 4; n++)
                    acc[m][n] = __builtin_amdgcn_mfma_f32_16x16x32_bf16(a[m], b[n], acc[m][n], 0, 0, 0);
            __builtin_amdgcn_s_setprio(0);
        }
        asm volatile("s_waitcnt vmcnt(0)" ::: "memory");
        __builtin_amdgcn_s_barrier();
        asm volatile("" ::: "memory");
    }

#pragma unroll
    for (int m = 0; m < 4; m++)
#pragma unroll
        for (int j = 0; j < 4; j++) {
            int rl = wm * 64 + m * 16 + g * 4 + j;
            if (rl < nrow) {
                int t = tok[rl];
                float gv = gat[rl];
                float* orow = out + (size_t)t * HD + n0 + wn * 64 + r;
#pragma unroll
                for (int n = 0; n < 4; n++)
                    atomicAdd(orow + n * 16, gv * acc[m][n][j]);
            }
        }
}

// ---------------- round-1 fused kernel (ws_size fallback) ----------------
__global__ __launch_bounds__(512, 2) void k_moe(
    const unsigned short* __restrict__ xb,
    const unsigned short* __restrict__ upt,
    const unsigned short* __restrict__ dnt,
    const int* __restrict__ counts,
    const int* __restrict__ tokL,
    const float* __restrict__ gateL,
    float* __restrict__ out) {
    __shared__ __align__(16) char lds[155648];
    char* xs = lds;
    char* hs = lds + 98304;
    char* ring = lds + 106496;

    const int e = blockIdx.x & 7;
    const int slot = blockIdx.x >> 3;
    const int cnt = counts[e];
    if (slot * 64 >= cnt) return;
    const int nrow = min(64, cnt - slot * 64);
    const int* tok = tokL + e * T_TOK + slot * 64;
    const float* gat = gateL + e * T_TOK + slot * 64;

    const int tid = threadIdx.x;
    const int lane = tid & 63;
    const int wid = tid >> 6;
    const int mi = wid >> 2, ni = wid & 3;

    const char* upe = (const char*)(upt + (size_t)e * ID * HD);
    const char* dne = (const char*)(dnt + (size_t)e * HD * ID);

    {
        int off = tid * 16;
#pragma unroll
        for (int s = 0; s < 12; s++) {
            int o = off + s * 8192;
            int m = o / 1536;
            int cb = o - m * 1536;
            int tk = (m < nrow) ? tok[m] : tok[0];
            const char* src = (const char*)xb + (size_t)tk * 1536 + (size_t)(cb ^ ((m & 7) << 4));
            gload16(src, xs + s * 8192 + wid * 1024);
        }
    }
    asm volatile("s_waitcnt vmcnt(0)" ::: "memory");
    __builtin_amdgcn_s_barrier();
    asm volatile("" ::: "memory");

    auto issue = [&](int s) {
        char* dst = ring + (s % 6) * 8192 + wid * 1024;
        int ci = s / 24;
        int ph = s - ci * 24;
        int row = tid >> 3;
        int cb = (tid & 7) << 4;
        int scb = cb ^ ((row & 7) << 4);
        const char* src;
        if (ci >= 48) src = upe;
        else if (ph < 12) src = upe + (size_t)(ci * 64 + row) * 1536 + ph * 128 + scb;
        else              src = dne + (size_t)((ph - 12) * 64 + row) * 6144 + ci * 128 + scb;
        gload16(src, dst);
    };

    f32x4 acc[2][12];
#pragma unroll
    for (int a = 0; a < 2; a++)
#pragma unroll
        for (int b = 0; b < 12; b++) acc[a][b] = (f32x4){0.f, 0.f, 0.f, 0.f};

    issue(0); issue(1); issue(2); issue(3);

    f32x4 acch[2];
    bf16x8 ha[2][2];

    for (int ci = 0; ci < 48; ci++) {
#pragma unroll
        for (int ks = 0; ks < 12; ks++) {
            issue(ci * 24 + ks + 4);
            asm volatile("s_waitcnt vmcnt(4)" ::: "memory");
            __builtin_amdgcn_s_barrier();
            asm volatile("" ::: "memory");
            char* buf = ring + (ks % 6) * 8192;
            if (ks == 0) { acch[0] = (f32x4){0.f,0.f,0.f,0.f}; acch[1] = (f32x4){0.f,0.f,0.f,0.f}; }
#pragma unroll
            for (int kr = 0; kr < 2; kr++) {
                int bn = ni * 16 + (lane & 15);
                int bo = ((kr * 32 + (lane >> 4) * 8) * 2) ^ ((bn & 7) << 4);
                bf16x8 bfrag = *(const bf16x8*)(buf + bn * 128 + bo);
#pragma unroll
                for (int mr = 0; mr < 2; mr++) {
                    int ar = mi * 32 + mr * 16 + (lane & 15);
                    int ao = ((ks * 64 + kr * 32 + (lane >> 4) * 8) * 2) ^ ((ar & 7) << 4);
                    bf16x8 afrag = *(const bf16x8*)(xs + ar * 1536 + ao);
                    acch[mr] = __builtin_amdgcn_mfma_f32_16x16x32_bf16(afrag, bfrag, acch[mr], 0, 0, 0);
                }
            }
            if (ks == 11) {
#pragma unroll
                for (int mr = 0; mr < 2; mr++) {
                    int col = ni * 16 + (lane & 15);
#pragma unroll
                    for (int r = 0; r < 4; r++) {
                        int m = mi * 32 + mr * 16 + (lane >> 4) * 4 + r;
                        float v = acch[mr][r];
                        *(unsigned short*)(hs + m * 128 + ((col * 2) ^ ((m & 7) << 4))) = f2bf(gelu_f(v));
                    }
                }
                asm volatile("s_waitcnt lgkmcnt(0)" ::: "memory");
            }
        }
#pragma unroll
        for (int j = 0; j < 12; j++) {
            issue(ci * 24 + 12 + j + 4);
            asm volatile("s_waitcnt vmcnt(4)" ::: "memory");
            __builtin_amdgcn_s_barrier();
            asm volatile("" ::: "memory");
            char* buf = ring + ((12 + j) % 6) * 8192;
            if (j == 0) {
#pragma unroll
                for (int mr = 0; mr < 2; mr++)
#pragma unroll
                    for (int kr = 0; kr < 2; kr++) {
                        int ar = mi * 32 + mr * 16 + (lane & 15);
                        int ao = ((kr * 32 + (lane >> 4) * 8) * 2) ^ ((ar & 7) << 4);
                        ha[mr][kr] = *(const bf16x8*)(hs + ar * 128 + ao);
                    }
            }
#pragma unroll
            for (int kr = 0; kr < 2; kr++) {
                int bn = ni * 16 + (lane & 15);
                int bo = ((kr * 32 + (lane >> 4) * 8) * 2) ^ ((bn & 7) << 4);
                bf16x8 bfrag = *(const bf16x8*)(buf + bn * 128 + bo);
#pragma unroll
                for (int mr = 0; mr < 2; mr++)
                    acc[mr][j] = __builtin_amdgcn_mfma_f32_16x16x32_bf16(ha[mr][kr], bfrag, acc[mr][j], 0, 0, 0);
            }
        }
    }

    int   t4[2][4];
    float g4[2][4];
#pragma unroll
    for (int mr = 0; mr < 2; mr++)
#pragma unroll
        for (int r = 0; r < 4; r++) {
            int m = mi * 32 + mr * 16 + (lane >> 4) * 4 + r;
            bool valid = m < nrow;
            t4[mr][r] = valid ? tok[m] : -1;
            g4[mr][r] = valid ? gat[m] : 0.f;
        }
#pragma unroll
    for (int mr = 0; mr < 2; mr++)
#pragma unroll
        for (int j = 0; j < 12; j++) {
            int colg = j * 64 + ni * 16 + (lane & 15);
#pragma unroll
            for (int r = 0; r < 4; r++) {
                if (t4[mr][r] >= 0)
                    atomicAdd(out + (size_t)t4[mr][r] * HD + colg, g4[mr][r] * acc[mr][j][r]);
            }
        }
}

extern "C" void kernel_launch(void* const* d_in, const int* in_sizes, int n_in,
                              void* d_out, int out_size, void* d_ws, size_t ws_size,
                              hipStream_t stream) {
    const float* x  = (const float*)d_in[0];
    const float* rw = (const float*)d_in[1];
    const float* uw = (const float*)d_in[2];
    const float* dw = (const float*)d_in[3];
    float* out = (float*)d_out;

    size_t off = 0;
    char* base = (char*)d_ws;
    auto alloc = [&](size_t bytes) -> char* {
        char* p = base + off;
        off += (bytes + 1023) & ~(size_t)1023;
        return p;
    };
    unsigned short* xb   = (unsigned short*)alloc((size_t)T_TOK * HD * 2);
    unsigned short* upt  = (unsigned short*)alloc((size_t)NE * ID * HD * 2);
    unsigned short* dnt  = (unsigned short*)alloc((size_t)NE * HD * ID * 2);
    int*   topE   = (int*)alloc((size_t)T_TOK * 2 * 4);
    float* topW   = (float*)alloc((size_t)T_TOK * 2 * 4);
    int*   counts = (int*)alloc(256);
    int*   tileE  = (int*)alloc(NTM * 4);
    int*   tileM0 = (int*)alloc(NTM * 4);
    int*   tokL   = (int*)alloc((size_t)NE * T_TOK * 4);
    float* gateL  = (float*)alloc((size_t)NE * T_TOK * 4);
    size_t fixed = off;

    // pick smallest segment count S (dividing 12) whose h-buffer fits
    const int cand[6] = {1, 2, 3, 4, 6, 12};
    int S = 0;
    size_t hrows = (size_t)NTM * 128;
    for (int i = 0; i < 6; i++) {
        size_t hb = hrows * (ID / cand[i]) * 2;
        if (fixed + hb <= ws_size) { S = cand[i]; break; }
    }
    unsigned short* h = (unsigned short*)(base + fixed);

    hipMemsetAsync(d_out, 0, (size_t)T_TOK * HD * 4, stream);
    hipMemsetAsync(counts, 0, 256, stream);

    k_cvt_x<<<(T_TOK * HD) / (256 * 4), 256, 0, stream>>>(x, xb);
    k_tp<<<dim3(ID / 64, HD / 64, NE), 256, 0, stream>>>(uw, upt, HD, ID);   // -> [i][h]
    k_tp<<<dim3(HD / 64, ID / 64, NE), 256, 0, stream>>>(dw, dnt, ID, HD);   // -> [h][i]
    k_router<<<T_TOK / 4, 256, 0, stream>>>(x, rw, topE, topW);
    k_scatter<<<T_TOK / 256, 256, 0, stream>>>(topE, topW, counts, tokL, gateL);

    if (S > 0) {
        int ldh = ID / S;          // h leading dim (elements)
        int ntn = ldh / 128;       // gemm1 n-tiles per segment
        int nk2 = ldh / 64;        // gemm2 k-steps per segment
        k_desc<<<1, 64, 0, stream>>>(counts, tileE, tileM0);
        for (int sg = 0; sg < S; sg++) {
            k_gemm1<<<NTM * ntn, 256, 0, stream>>>(xb, upt, tokL, counts, tileE, tileM0,
                                                   h, sg * ldh, ntn, ldh);
            k_gemm2<<<NTM * 6, 256, 0, stream>>>(h, dnt, tokL, gateL, counts, tileE, tileM0,
                                                 out, sg * ldh, ldh, nk2);
        }
    } else {
        k_moe<<<2048, 512, 0, stream>>>(xb, upt, dnt, counts, tokL, gateL, out);
    }
}

// Round 7
// 790.854 us; speedup vs baseline: 1.1204x; 1.1204x over previous
//
#include <hip/hip_runtime.h>

typedef short bf16x8 __attribute__((ext_vector_type(8)));
typedef float f32x4  __attribute__((ext_vector_type(4)));

#define T_TOK 16384
#define HD 768
#define ID 3072
#define NE 8
#define NT1MAX 136       // max 256-row tiles: 32768/256 + 8 partials

__device__ __forceinline__ unsigned short f2bf(float f) {
    unsigned int u = __float_as_uint(f);
    unsigned int r = (u + 0x7FFFu + ((u >> 16) & 1u)) >> 16;   // RNE
    return (unsigned short)r;
}

__device__ __forceinline__ void gload16(const void* g, void* l) {
    __builtin_amdgcn_global_load_lds(
        (const __attribute__((address_space(1))) void*)g,
        (__attribute__((address_space(3))) void*)l, 16, 0, 0);
}

__device__ __forceinline__ float gelu_f(float x) {
    // exact-GELU via A&S 7.1.26 erf approx (|err| <= 1.5e-7, invisible at bf16)
    float z = fabsf(x) * 0.70710678118f;
    float t = 1.0f / fmaf(0.3275911f, z, 1.0f);
    float p = t * fmaf(t, fmaf(t, fmaf(t, fmaf(t, 1.061405429f, -1.453152027f),
                                       1.421413741f), -0.284496736f), 0.254829592f);
    float e = 1.0f - p * __expf(-z * z);
    float erfv = (x >= 0.f) ? e : -e;
    return 0.5f * x * (1.0f + erfv);
}

__device__ __forceinline__ int xcd_swz(int bid, int nwg) {
    // bijective XCD-chunked remap (m204)
    int q = nwg >> 3, rr = nwg & 7;
    int xcd = bid & 7, seq = bid >> 3;
    return (xcd < rr ? xcd * (q + 1) : rr * (q + 1) + (xcd - rr) * q) + seq;
}

// ---------------- x f32 -> bf16 ----------------
__global__ __launch_bounds__(256) void k_cvt_x(const float* __restrict__ x,
                                               unsigned short* __restrict__ xb) {
    int i = blockIdx.x * 256 + threadIdx.x;
    float4 v = ((const float4*)x)[i];
    ushort4 o;
    o.x = f2bf(v.x); o.y = f2bf(v.y); o.z = f2bf(v.z); o.w = f2bf(v.w);
    ((ushort4*)xb)[i] = o;
}

// ---------------- transpose + cvt: in [E][R][C] f32 -> out [E][C][R] bf16 ----
__global__ __launch_bounds__(256) void k_tp(const float* __restrict__ in,
                                            unsigned short* __restrict__ out,
                                            int R, int C) {
    __shared__ float t[64][65];
    const float* ine = in + (size_t)blockIdx.z * R * C;
    unsigned short* oute = out + (size_t)blockIdx.z * R * C;
    int c0 = blockIdx.x * 64, r0 = blockIdx.y * 64;
    int lc = threadIdx.x & 63, lr4 = threadIdx.x >> 6;
#pragma unroll
    for (int i = 0; i < 16; i++) {
        int r = i * 4 + lr4;
        t[r][lc] = ine[(size_t)(r0 + r) * C + c0 + lc];
    }
    __syncthreads();
#pragma unroll
    for (int i = 0; i < 16; i++) {
        int r = i * 4 + lr4;
        oute[(size_t)(c0 + r) * R + r0 + lc] = f2bf(t[lc][r]);
    }
}

// ---------------- router: wave per token, f32 ----------------
__global__ __launch_bounds__(256) void k_router(const float* __restrict__ x,
                                                const float* __restrict__ rw,
                                                int* __restrict__ topE,
                                                float* __restrict__ topW) {
    __shared__ float lrw[NE * HD];
    for (int i = threadIdx.x; i < NE * HD; i += 256) lrw[i] = rw[i];
    __syncthreads();
    int lane = threadIdx.x & 63;
    int t = blockIdx.x * 4 + (threadIdx.x >> 6);
    const float* xr = x + (size_t)t * HD;
    float acc[NE] = {0, 0, 0, 0, 0, 0, 0, 0};
    for (int h = lane; h < HD; h += 64) {
        float xv = xr[h];
#pragma unroll
        for (int e = 0; e < NE; e++) acc[e] = fmaf(xv, lrw[e * HD + h], acc[e]);
    }
#pragma unroll
    for (int e = 0; e < NE; e++) {
        float v = acc[e];
#pragma unroll
        for (int o = 32; o > 0; o >>= 1) v += __shfl_xor(v, o, 64);
        acc[e] = v;
    }
    if (lane == 0) {
        int e1 = 0; float l1 = acc[0];
#pragma unroll
        for (int e = 1; e < NE; e++) if (acc[e] > l1) { l1 = acc[e]; e1 = e; }
        int e2 = -1; float l2 = -1e30f;
#pragma unroll
        for (int e = 0; e < NE; e++) if (e != e1 && acc[e] > l2) { l2 = acc[e]; e2 = e; }
        float ex = expf(l2 - l1);
        float w1 = 1.0f / (1.0f + ex);
        topE[2 * t] = e1; topE[2 * t + 1] = e2;
        topW[2 * t] = w1; topW[2 * t + 1] = ex * w1;
    }
}

// ---------------- scatter into per-expert lists ----------------
__global__ __launch_bounds__(256) void k_scatter(const int* __restrict__ topE,
                                                 const float* __restrict__ topW,
                                                 int* __restrict__ counts,
                                                 int* __restrict__ tokL,
                                                 float* __restrict__ gateL) {
    __shared__ int lc[NE], lbase[NE];
    if (threadIdx.x < NE) lc[threadIdx.x] = 0;
    __syncthreads();
    int t = blockIdx.x * 256 + threadIdx.x;
    int e1 = topE[2 * t], e2 = topE[2 * t + 1];
    int p1 = atomicAdd(&lc[e1], 1);
    int p2 = atomicAdd(&lc[e2], 1);
    __syncthreads();
    if (threadIdx.x < NE) lbase[threadIdx.x] = atomicAdd(&counts[threadIdx.x], lc[threadIdx.x]);
    __syncthreads();
    int q1 = lbase[e1] + p1, q2 = lbase[e2] + p2;
    tokL[e1 * T_TOK + q1] = t;  gateL[e1 * T_TOK + q1] = topW[2 * t];
    tokL[e2 * T_TOK + q2] = t;  gateL[e2 * T_TOK + q2] = topW[2 * t + 1];
}

// ---------------- tile descriptor build: 256-row tiles ----------------
__global__ void k_desc(const int* __restrict__ counts, int* __restrict__ tileE,
                       int* __restrict__ tileM0) {
    if (threadIdx.x == 0 && blockIdx.x == 0) {
        int tl = 0;
        for (int e = 0; e < NE; e++) {
            int c = counts[e];
            int nt = (c + 255) >> 8;
            for (int t = 0; t < nt; t++) { tileE[tl] = e; tileM0[tl] = t << 8; tl++; }
        }
        for (; tl < NT1MAX; tl++) { tileE[tl] = -1; tileM0[tl] = 0; }
    }
}

// ================= 8-phase grouped GEMM1: h_seg = gelu( Xg @ up_seg^T ) =================
// 256x256 tile, BK=64, 8 waves (2M x 4N), 128KB LDS = 2-K-tile dbuf.
// Per K-tile T (parity par=T&1), 4 phases; each: {ds_read subtile | stage half-tile} ->
// barrier -> lgkmcnt(0)+sched_barrier -> setprio+16 MFMA -> barrier.
// Stage schedule: P1: Bh1(T+1)+Ah0(T+1); P2: Ah1(T+1); P4: Bh0(T+2).
// CHECKPOINT (race-fix r7): vmcnt(2) at P4 AFTER the stage issue, BEFORE the mid barrier
// -> retires all 8 loads of tile T+1, floats only Bh0(T+2); tile T+1's reads are >=1
// barrier after every wave's checkpoint (cross-wave safe). Reads at P1-top have no vmcnt.
// LDS chunks: 1KB = 16 rows x 64B, [kgrp4][row16]x16B -> gload dst linear, ds_read
// contiguous-1KB (conflict-free, G21-safe).
__global__ __launch_bounds__(512, 2) void k_gemm1(
    const unsigned short* __restrict__ xb,
    const unsigned short* __restrict__ upt,     // [E][I][H] bf16
    const int* __restrict__ tokL,
    const int* __restrict__ counts,
    const int* __restrict__ tileE,
    const int* __restrict__ tileM0,
    unsigned short* __restrict__ h,             // [NT1MAX*256][ldh]
    int seg, int ntn, int ldh) {
    __shared__ __align__(16) char lds[131072];
    constexpr int NKT = HD / 64;                // 12
    int L = xcd_swz(blockIdx.x, gridDim.x);
    int mt = L / ntn, ntl = L - mt * ntn;
    int e = tileE[mt];
    if (e < 0) return;
    int m0 = tileM0[mt];
    int nrow = min(256, counts[e] - m0);
    const int* tok = tokL + e * T_TOK + m0;
    int n0 = (seg * ntn + ntl) * 256;

    const int tid = threadIdx.x, lane = tid & 63, wid = tid >> 6;
    const int wm = wid >> 2, wn = wid & 3;
    const int g = lane >> 4, r = lane & 15;
    const int kr = wid & 1;

    const char* bsl = (const char*)(upt + (size_t)e * ID * HD);
    const char* aB[2][2];
    const char* bB[2][2];
#pragma unroll
    for (int hh = 0; hh < 2; hh++)
#pragma unroll
        for (int j = 0; j < 2; j++) {
            int row = (hh * 8 + j * 4 + (wid >> 1)) * 16 + r;
            aB[hh][j] = (const char*)xb + (size_t)tok[row < nrow ? row : 0] * (HD * 2) + kr * 64 + g * 16;
            bB[hh][j] = bsl + (size_t)(n0 + row) * (HD * 2) + kr * 64 + g * 16;
        }

    auto stgA = [&](int T_, int hh_) {
        int p_ = (T_ & 1) * 65536;
        gload16(aB[hh_][0] + T_ * 128, lds + p_ + (hh_ * 16 + wid) * 1024);
        gload16(aB[hh_][1] + T_ * 128, lds + p_ + (hh_ * 16 + 8 + wid) * 1024);
    };
    auto stgB = [&](int T_, int hh_) {
        int p_ = (T_ & 1) * 65536 + 32768;
        gload16(bB[hh_][0] + T_ * 128, lds + p_ + (hh_ * 16 + wid) * 1024);
        gload16(bB[hh_][1] + T_ * 128, lds + p_ + (hh_ * 16 + 8 + wid) * 1024);
    };
    const int foff = g * 256 + r * 16;
    auto AO = [&](int mf, int krr, int par) { return par * 65536 + ((wm * 8 + mf) * 2 + krr) * 1024 + foff; };
    auto BO = [&](int nf, int krr, int par) { return par * 65536 + 32768 + ((wn * 4 + nf) * 2 + krr) * 1024 + foff; };

    f32x4 acc[8][4];
#pragma unroll
    for (int m = 0; m < 8; m++)
#pragma unroll
        for (int n = 0; n < 4; n++) acc[m][n] = (f32x4){0.f, 0.f, 0.f, 0.f};

    // prologue: tile0 fully + Bh0(1); checkpoint retires tile0, floats Bh0(1)
    stgB(0, 0); stgB(0, 1); stgA(0, 0); stgA(0, 1); stgB(1, 0);
    asm volatile("s_waitcnt vmcnt(2)" ::: "memory");
    __builtin_amdgcn_s_barrier();
    asm volatile("" ::: "memory");

    bf16x8 a[4], b[4];
    for (int T = 0; T < NKT; ++T) {
        int par = T & 1;
        // ---------- P1 ----------
#pragma unroll
        for (int i = 0; i < 4; i++) a[i] = *(const bf16x8*)(lds + AO(i, 0, par));
#pragma unroll
        for (int i = 0; i < 4; i++) b[i] = *(const bf16x8*)(lds + BO(i, 0, par));
        if (T + 1 < NKT) { stgB(T + 1, 1); stgA(T + 1, 0); }
        asm volatile("" ::: "memory");
        __builtin_amdgcn_s_barrier();
        asm volatile("s_waitcnt lgkmcnt(0)" ::: "memory");
        __builtin_amdgcn_sched_barrier(0);
        __builtin_amdgcn_s_setprio(1);
#pragma unroll
        for (int m = 0; m < 4; m++)
#pragma unroll
            for (int n = 0; n < 4; n++)
                acc[m][n] = __builtin_amdgcn_mfma_f32_16x16x32_bf16(a[m], b[n], acc[m][n], 0, 0, 0);
        __builtin_amdgcn_s_setprio(0);
        asm volatile("" ::: "memory");
        __builtin_amdgcn_s_barrier();
        // ---------- P2 ----------
#pragma unroll
        for (int i = 0; i < 4; i++) a[i] = *(const bf16x8*)(lds + AO(4 + i, 0, par));
        if (T + 1 < NKT) stgA(T + 1, 1);
        asm volatile("" ::: "memory");
        __builtin_amdgcn_s_barrier();
        asm volatile("s_waitcnt lgkmcnt(0)" ::: "memory");
        __builtin_amdgcn_sched_barrier(0);
        __builtin_amdgcn_s_setprio(1);
#pragma unroll
        for (int m = 0; m < 4; m++)
#pragma unroll
            for (int n = 0; n < 4; n++)
                acc[4 + m][n] = __builtin_amdgcn_mfma_f32_16x16x32_bf16(a[m], b[n], acc[4 + m][n], 0, 0, 0);
        __builtin_amdgcn_s_setprio(0);
        asm volatile("" ::: "memory");
        __builtin_amdgcn_s_barrier();
        // ---------- P3 ----------
#pragma unroll
        for (int i = 0; i < 4; i++) a[i] = *(const bf16x8*)(lds + AO(i, 1, par));
#pragma unroll
        for (int i = 0; i < 4; i++) b[i] = *(const bf16x8*)(lds + BO(i, 1, par));
        asm volatile("" ::: "memory");
        __builtin_amdgcn_s_barrier();
        asm volatile("s_waitcnt lgkmcnt(0)" ::: "memory");
        __builtin_amdgcn_sched_barrier(0);
        __builtin_amdgcn_s_setprio(1);
#pragma unroll
        for (int m = 0; m < 4; m++)
#pragma unroll
            for (int n = 0; n < 4; n++)
                acc[m][n] = __builtin_amdgcn_mfma_f32_16x16x32_bf16(a[m], b[n], acc[m][n], 0, 0, 0);
        __builtin_amdgcn_s_setprio(0);
        asm volatile("" ::: "memory");
        __builtin_amdgcn_s_barrier();
        // ---------- P4 ----------
#pragma unroll
        for (int i = 0; i < 4; i++) a[i] = *(const bf16x8*)(lds + AO(4 + i, 1, par));
        { int Ts = (T + 2 < NKT) ? T + 2 : NKT - 1; stgB(Ts, 0); }  // dummy at tail keeps vmcnt invariant
        asm volatile("s_waitcnt vmcnt(2)" ::: "memory");            // CHECKPOINT: tile T+1 fully landed
        __builtin_amdgcn_s_barrier();
        asm volatile("s_waitcnt lgkmcnt(0)" ::: "memory");
        __builtin_amdgcn_sched_barrier(0);
        __builtin_amdgcn_s_setprio(1);
#pragma unroll
        for (int m = 0; m < 4; m++)
#pragma unroll
            for (int n = 0; n < 4; n++)
                acc[4 + m][n] = __builtin_amdgcn_mfma_f32_16x16x32_bf16(a[m], b[n], acc[4 + m][n], 0, 0, 0);
        __builtin_amdgcn_s_setprio(0);
        asm volatile("" ::: "memory");
        __builtin_amdgcn_s_barrier();
    }
    asm volatile("s_waitcnt vmcnt(0)" ::: "memory");

#pragma unroll
    for (int m = 0; m < 8; m++)
#pragma unroll
        for (int jj = 0; jj < 4; jj++) {
            int rl = wm * 128 + m * 16 + g * 4 + jj;
            if (rl < nrow) {
                unsigned short* hr = h + (size_t)(mt * 256 + rl) * ldh + ntl * 256 + wn * 64 + r;
#pragma unroll
                for (int n = 0; n < 4; n++) hr[n * 16] = f2bf(gelu_f(acc[m][n][jj]));
            }
        }
}

// ========= 8-phase grouped GEMM2: out[tok] += gate * ( h_seg @ down_seg^T ) =========
__global__ __launch_bounds__(512, 2) void k_gemm2(
    const unsigned short* __restrict__ h,       // [NT1MAX*256][ldh]
    const unsigned short* __restrict__ dnt,     // [E][H][I] bf16
    const int* __restrict__ tokL,
    const float* __restrict__ gateL,
    const int* __restrict__ counts,
    const int* __restrict__ tileE,
    const int* __restrict__ tileM0,
    float* __restrict__ out,
    int seg, int ldh, int nkt) {
    __shared__ __align__(16) char lds[131072];
    int L = xcd_swz(blockIdx.x, gridDim.x);
    int mt = L / 3, ntl = L - mt * 3;
    int e = tileE[mt];
    if (e < 0) return;
    int m0 = tileM0[mt];
    int nrow = min(256, counts[e] - m0);
    const int* tok = tokL + e * T_TOK + m0;
    const float* gat = gateL + e * T_TOK + m0;
    int n0 = ntl * 256;

    const int tid = threadIdx.x, lane = tid & 63, wid = tid >> 6;
    const int wm = wid >> 2, wn = wid & 3;
    const int g = lane >> 4, r = lane & 15;
    const int kr = wid & 1;

    const char* bsl = (const char*)(dnt + (size_t)e * ID * HD) + (size_t)seg * ldh * 2;
    const char* aB[2][2];
    const char* bB[2][2];
#pragma unroll
    for (int hh = 0; hh < 2; hh++)
#pragma unroll
        for (int j = 0; j < 2; j++) {
            int row = (hh * 8 + j * 4 + (wid >> 1)) * 16 + r;
            aB[hh][j] = (const char*)h + (size_t)(mt * 256 + row) * ldh * 2 + kr * 64 + g * 16;  // pad rows: garbage, row-isolated
            bB[hh][j] = bsl + (size_t)(n0 + row) * (ID * 2) + kr * 64 + g * 16;
        }

    auto stgA = [&](int T_, int hh_) {
        int p_ = (T_ & 1) * 65536;
        gload16(aB[hh_][0] + T_ * 128, lds + p_ + (hh_ * 16 + wid) * 1024);
        gload16(aB[hh_][1] + T_ * 128, lds + p_ + (hh_ * 16 + 8 + wid) * 1024);
    };
    auto stgB = [&](int T_, int hh_) {
        int p_ = (T_ & 1) * 65536 + 32768;
        gload16(bB[hh_][0] + T_ * 128, lds + p_ + (hh_ * 16 + wid) * 1024);
        gload16(bB[hh_][1] + T_ * 128, lds + p_ + (hh_ * 16 + 8 + wid) * 1024);
    };
    const int foff = g * 256 + r * 16;
    auto AO = [&](int mf, int krr, int par) { return par * 65536 + ((wm * 8 + mf) * 2 + krr) * 1024 + foff; };
    auto BO = [&](int nf, int krr, int par) { return par * 65536 + 32768 + ((wn * 4 + nf) * 2 + krr) * 1024 + foff; };

    f32x4 acc[8][4];
#pragma unroll
    for (int m = 0; m < 8; m++)
#pragma unroll
        for (int n = 0; n < 4; n++) acc[m][n] = (f32x4){0.f, 0.f, 0.f, 0.f};

    stgB(0, 0); stgB(0, 1); stgA(0, 0); stgA(0, 1); stgB(1, 0);
    asm volatile("s_waitcnt vmcnt(2)" ::: "memory");
    __builtin_amdgcn_s_barrier();
    asm volatile("" ::: "memory");

    bf16x8 a[4], b[4];
    for (int T = 0; T < nkt; ++T) {
        int par = T & 1;
        // ---------- P1 ----------
#pragma unroll
        for (int i = 0; i < 4; i++) a[i] = *(const bf16x8*)(lds + AO(i, 0, par));
#pragma unroll
        for (int i = 0; i < 4; i++) b[i] = *(const bf16x8*)(lds + BO(i, 0, par));
        if (T + 1 < nkt) { stgB(T + 1, 1); stgA(T + 1, 0); }
        asm volatile("" ::: "memory");
        __builtin_amdgcn_s_barrier();
        asm volatile("s_waitcnt lgkmcnt(0)" ::: "memory");
        __builtin_amdgcn_sched_barrier(0);
        __builtin_amdgcn_s_setprio(1);
#pragma unroll
        for (int m = 0; m < 4; m++)
#pragma unroll
            for (int n = 0; n < 4; n++)
                acc[m][n] = __builtin_amdgcn_mfma_f32_16x16x32_bf16(a[m], b[n], acc[m][n], 0, 0, 0);
        __builtin_amdgcn_s_setprio(0);
        asm volatile("" ::: "memory");
        __builtin_amdgcn_s_barrier();
        // ---------- P2 ----------
#pragma unroll
        for (int i = 0; i < 4; i++) a[i] = *(const bf16x8*)(lds + AO(4 + i, 0, par));
        if (T + 1 < nkt) stgA(T + 1, 1);
        asm volatile("" ::: "memory");
        __builtin_amdgcn_s_barrier();
        asm volatile("s_waitcnt lgkmcnt(0)" ::: "memory");
        __builtin_amdgcn_sched_barrier(0);
        __builtin_amdgcn_s_setprio(1);
#pragma unroll
        for (int m = 0; m < 4; m++)
#pragma unroll
            for (int n = 0; n < 4; n++)
                acc[4 + m][n] = __builtin_amdgcn_mfma_f32_16x16x32_bf16(a[m], b[n], acc[4 + m][n], 0, 0, 0);
        __builtin_amdgcn_s_setprio(0);
        asm volatile("" ::: "memory");
        __builtin_amdgcn_s_barrier();
        // ---------- P3 ----------
#pragma unroll
        for (int i = 0; i < 4; i++) a[i] = *(const bf16x8*)(lds + AO(i, 1, par));
#pragma unroll
        for (int i = 0; i < 4; i++) b[i] = *(const bf16x8*)(lds + BO(i, 1, par));
        asm volatile("" ::: "memory");
        __builtin_amdgcn_s_barrier();
        asm volatile("s_waitcnt lgkmcnt(0)" ::: "memory");
        __builtin_amdgcn_sched_barrier(0);
        __builtin_amdgcn_s_setprio(1);
#pragma unroll
        for (int m = 0; m < 4; m++)
#pragma unroll
            for (int n = 0; n < 4; n++)
                acc[m][n] = __builtin_amdgcn_mfma_f32_16x16x32_bf16(a[m], b[n], acc[m][n], 0, 0, 0);
        __builtin_amdgcn_s_setprio(0);
        asm volatile("" ::: "memory");
        __builtin_amdgcn_s_barrier();
        // ---------- P4 ----------
#pragma unroll
        for (int i = 0; i < 4; i++) a[i] = *(const bf16x8*)(lds + AO(4 + i, 1, par));
        { int Ts = (T + 2 < nkt) ? T + 2 : nkt - 1; stgB(Ts, 0); }
        asm volatile("s_waitcnt vmcnt(2)" ::: "memory");            // CHECKPOINT: tile T+1 fully landed
        __builtin_amdgcn_s_barrier();
        asm volatile("s_waitcnt lgkmcnt(0)" ::: "memory");
        __builtin_amdgcn_sched_barrier(0);
        __builtin_amdgcn_s_setprio(1);
#pragma unroll
        for (int m = 0; m < 4; m++)
#pragma unroll
            for (int n = 0; n < 4; n++)
                acc[4 + m][n] = __builtin_amdgcn_mfma_f32_16x16x32_bf16(a[m], b[n], acc[4 + m][n], 0, 0, 0);
        __builtin_amdgcn_s_setprio(0);
        asm volatile("" ::: "memory");
        __builtin_amdgcn_s_barrier();
    }
    asm volatile("s_waitcnt vmcnt(0)" ::: "memory");

#pragma unroll
    for (int m = 0; m < 8; m++)
#pragma unroll
        for (int jj = 0; jj < 4; jj++) {
            int rl = wm * 128 + m * 16 + g * 4 + jj;
            if (rl < nrow) {
                int t = tok[rl];
                float gv = gat[rl];
                float* orow = out + (size_t)t * HD + n0 + wn * 64 + r;
#pragma unroll
                for (int n = 0; n < 4; n++)
                    atomicAdd(orow + n * 16, gv * acc[m][n][jj]);
            }
        }
}

// ---------------- round-1 fused kernel (ws_size fallback) ----------------
__global__ __launch_bounds__(512, 2) void k_moe(
    const unsigned short* __restrict__ xb,
    const unsigned short* __restrict__ upt,
    const unsigned short* __restrict__ dnt,
    const int* __restrict__ counts,
    const int* __restrict__ tokL,
    const float* __restrict__ gateL,
    float* __restrict__ out) {
    __shared__ __align__(16) char lds[155648];
    char* xs = lds;
    char* hs = lds + 98304;
    char* ring = lds + 106496;

    const int e = blockIdx.x & 7;
    const int slot = blockIdx.x >> 3;
    const int cnt = counts[e];
    if (slot * 64 >= cnt) return;
    const int nrow = min(64, cnt - slot * 64);
    const int* tok = tokL + e * T_TOK + slot * 64;
    const float* gat = gateL + e * T_TOK + slot * 64;

    const int tid = threadIdx.x;
    const int lane = tid & 63;
    const int wid = tid >> 6;
    const int mi = wid >> 2, ni = wid & 3;

    const char* upe = (const char*)(upt + (size_t)e * ID * HD);
    const char* dne = (const char*)(dnt + (size_t)e * HD * ID);

    {
        int off = tid * 16;
#pragma unroll
        for (int s = 0; s < 12; s++) {
            int o = off + s * 8192;
            int m = o / 1536;
            int cb = o - m * 1536;
            int tk = (m < nrow) ? tok[m] : tok[0];
            const char* src = (const char*)xb + (size_t)tk * 1536 + (size_t)(cb ^ ((m & 7) << 4));
            gload16(src, xs + s * 8192 + wid * 1024);
        }
    }
    asm volatile("s_waitcnt vmcnt(0)" ::: "memory");
    __builtin_amdgcn_s_barrier();
    asm volatile("" ::: "memory");

    auto issue = [&](int s) {
        char* dst = ring + (s % 6) * 8192 + wid * 1024;
        int ci = s / 24;
        int ph = s - ci * 24;
        int row = tid >> 3;
        int cb = (tid & 7) << 4;
        int scb = cb ^ ((row & 7) << 4);
        const char* src;
        if (ci >= 48) src = upe;
        else if (ph < 12) src = upe + (size_t)(ci * 64 + row) * 1536 + ph * 128 + scb;
        else              src = dne + (size_t)((ph - 12) * 64 + row) * 6144 + ci * 128 + scb;
        gload16(src, dst);
    };

    f32x4 acc[2][12];
#pragma unroll
    for (int a = 0; a < 2; a++)
#pragma unroll
        for (int b = 0; b < 12; b++) acc[a][b] = (f32x4){0.f, 0.f, 0.f, 0.f};

    issue(0); issue(1); issue(2); issue(3);

    f32x4 acch[2];
    bf16x8 ha[2][2];

    for (int ci = 0; ci < 48; ci++) {
#pragma unroll
        for (int ks = 0; ks < 12; ks++) {
            issue(ci * 24 + ks + 4);
            asm volatile("s_waitcnt vmcnt(4)" ::: "memory");
            __builtin_amdgcn_s_barrier();
            asm volatile("" ::: "memory");
            char* buf = ring + (ks % 6) * 8192;
            if (ks == 0) { acch[0] = (f32x4){0.f,0.f,0.f,0.f}; acch[1] = (f32x4){0.f,0.f,0.f,0.f}; }
#pragma unroll
            for (int kkr = 0; kkr < 2; kkr++) {
                int bn = ni * 16 + (lane & 15);
                int bo = ((kkr * 32 + (lane >> 4) * 8) * 2) ^ ((bn & 7) << 4);
                bf16x8 bfrag = *(const bf16x8*)(buf + bn * 128 + bo);
#pragma unroll
                for (int mr = 0; mr < 2; mr++) {
                    int ar = mi * 32 + mr * 16 + (lane & 15);
                    int ao = ((ks * 64 + kkr * 32 + (lane >> 4) * 8) * 2) ^ ((ar & 7) << 4);
                    bf16x8 afrag = *(const bf16x8*)(xs + ar * 1536 + ao);
                    acch[mr] = __builtin_amdgcn_mfma_f32_16x16x32_bf16(afrag, bfrag, acch[mr], 0, 0, 0);
                }
            }
            if (ks == 11) {
#pragma unroll
                for (int mr = 0; mr < 2; mr++) {
                    int col = ni * 16 + (lane & 15);
#pragma unroll
                    for (int rr = 0; rr < 4; rr++) {
                        int m = mi * 32 + mr * 16 + (lane >> 4) * 4 + rr;
                        float v = acch[mr][rr];
                        *(unsigned short*)(hs + m * 128 + ((col * 2) ^ ((m & 7) << 4))) = f2bf(gelu_f(v));
                    }
                }
                asm volatile("s_waitcnt lgkmcnt(0)" ::: "memory");
            }
        }
#pragma unroll
        for (int j = 0; j < 12; j++) {
            issue(ci * 24 + 12 + j + 4);
            asm volatile("s_waitcnt vmcnt(4)" ::: "memory");
            __builtin_amdgcn_s_barrier();
            asm volatile("" ::: "memory");
            char* buf = ring + ((12 + j) % 6) * 8192;
            if (j == 0) {
#pragma unroll
                for (int mr = 0; mr < 2; mr++)
#pragma unroll
                    for (int kkr = 0; kkr < 2; kkr++) {
                        int ar = mi * 32 + mr * 16 + (lane & 15);
                        int ao = ((kkr * 32 + (lane >> 4) * 8) * 2) ^ ((ar & 7) << 4);
                        ha[mr][kkr] = *(const bf16x8*)(hs + ar * 128 + ao);
                    }
            }
#pragma unroll
            for (int kkr = 0; kkr < 2; kkr++) {
                int bn = ni * 16 + (lane & 15);
                int bo = ((kkr * 32 + (lane >> 4) * 8) * 2) ^ ((bn & 7) << 4);
                bf16x8 bfrag = *(const bf16x8*)(buf + bn * 128 + bo);
#pragma unroll
                for (int mr = 0; mr < 2; mr++)
                    acc[mr][j] = __builtin_amdgcn_mfma_f32_16x16x32_bf16(ha[mr][kkr], bfrag, acc[mr][j], 0, 0, 0);
            }
        }
    }

    int   t4[2][4];
    float g4[2][4];
#pragma unroll
    for (int mr = 0; mr < 2; mr++)
#pragma unroll
        for (int rr = 0; rr < 4; rr++) {
            int m = mi * 32 + mr * 16 + (lane >> 4) * 4 + rr;
            bool valid = m < nrow;
            t4[mr][rr] = valid ? tok[m] : -1;
            g4[mr][rr] = valid ? gat[m] : 0.f;
        }
#pragma unroll
    for (int mr = 0; mr < 2; mr++)
#pragma unroll
        for (int j = 0; j < 12; j++) {
            int colg = j * 64 + ni * 16 + (lane & 15);
#pragma unroll
            for (int rr = 0; rr < 4; rr++) {
                if (t4[mr][rr] >= 0)
                    atomicAdd(out + (size_t)t4[mr][rr] * HD + colg, g4[mr][rr] * acc[mr][j][rr]);
            }
        }
}

extern "C" void kernel_launch(void* const* d_in, const int* in_sizes, int n_in,
                              void* d_out, int out_size, void* d_ws, size_t ws_size,
                              hipStream_t stream) {
    const float* x  = (const float*)d_in[0];
    const float* rw = (const float*)d_in[1];
    const float* uw = (const float*)d_in[2];
    const float* dw = (const float*)d_in[3];
    float* out = (float*)d_out;

    size_t off = 0;
    char* base = (char*)d_ws;
    auto alloc = [&](size_t bytes) -> char* {
        char* p = base + off;
        off += (bytes + 1023) & ~(size_t)1023;
        return p;
    };
    unsigned short* xb   = (unsigned short*)alloc((size_t)T_TOK * HD * 2);
    unsigned short* upt  = (unsigned short*)alloc((size_t)NE * ID * HD * 2);
    unsigned short* dnt  = (unsigned short*)alloc((size_t)NE * HD * ID * 2);
    int*   topE   = (int*)alloc((size_t)T_TOK * 2 * 4);
    float* topW   = (float*)alloc((size_t)T_TOK * 2 * 4);
    int*   counts = (int*)alloc(256);
    int*   tileE  = (int*)alloc(NT1MAX * 4);
    int*   tileM0 = (int*)alloc(NT1MAX * 4);
    int*   tokL   = (int*)alloc((size_t)NE * T_TOK * 4);
    float* gateL  = (float*)alloc((size_t)NE * T_TOK * 4);
    size_t fixed = off;

    // pick smallest segment count S (dividing 12) whose h-buffer fits
    const int cand[6] = {1, 2, 3, 4, 6, 12};
    int S = 0;
    size_t hrows = (size_t)NT1MAX * 256;
    for (int i = 0; i < 6; i++) {
        size_t hb = hrows * (ID / cand[i]) * 2;
        if (fixed + hb <= ws_size) { S = cand[i]; break; }
    }
    unsigned short* h = (unsigned short*)(base + fixed);

    hipMemsetAsync(d_out, 0, (size_t)T_TOK * HD * 4, stream);
    hipMemsetAsync(counts, 0, 256, stream);

    k_cvt_x<<<(T_TOK * HD) / (256 * 4), 256, 0, stream>>>(x, xb);
    k_tp<<<dim3(ID / 64, HD / 64, NE), 256, 0, stream>>>(uw, upt, HD, ID);   // -> [i][h]
    k_tp<<<dim3(HD / 64, ID / 64, NE), 256, 0, stream>>>(dw, dnt, ID, HD);   // -> [h][i]
    k_router<<<T_TOK / 4, 256, 0, stream>>>(x, rw, topE, topW);
    k_scatter<<<T_TOK / 256, 256, 0, stream>>>(topE, topW, counts, tokL, gateL);

    if (S > 0) {
        int ldh = ID / S;          // h leading dim (elements)
        int ntn = ldh / 256;       // gemm1 n-tiles per segment
        int nkt = ldh / 64;        // gemm2 K-tiles per segment
        k_desc<<<1, 64, 0, stream>>>(counts, tileE, tileM0);
        for (int sg = 0; sg < S; sg++) {
            k_gemm1<<<NT1MAX * ntn, 512, 0, stream>>>(xb, upt, tokL, counts, tileE, tileM0,
                                                      h, sg, ntn, ldh);
            k_gemm2<<<NT1MAX * 3, 512, 0, stream>>>(h, dnt, tokL, gateL, counts, tileE, tileM0,
                                                    out, sg, ldh, nkt);
        }
    } else {
        k_moe<<<2048, 512, 0, stream>>>(xb, upt, dnt, counts, tokL, gateL, out);
    }
}